// Round 2
// baseline (784.460 us; speedup 1.0000x reference)
//
#include <hip/hip_runtime.h>
#include <math.h>

#define C_DIM 16
#define B_DIM 128
#define H_DIM 512
#define W_DIM 512
#define HW (H_DIM * W_DIM)      // 262144
#define BPS 16                  // blocks (chunks) per sample
#define TPB 256
#define VEC_PER_CHUNK (HW / 4 / BPS)   // 4096 float4 per block -> 16 iters/thread

typedef float f4 __attribute__((ext_vector_type(4)));

// Workspace layout (re-poisoned by harness each iteration; the flag protocol
// below is correct for any dword-uniform initial contents, and cannot FAULT
// for arbitrary contents thanks to the idx clamp in the gather).
struct Ws {
    unsigned long long part[B_DIM * BPS]; // 16 KB partial argmax keys
    unsigned int orf[B_DIM];              // per-sample OR-completion word
    unsigned int andf[B_DIM];             // per-sample AND-completion word
    unsigned int gor[4];                  // global (128-sample) OR words
    unsigned int gand[4];                 // global AND words
    float sse[B_DIM];                     // per-sample squared-error sums
};

__device__ __forceinline__ unsigned int mono_bits(float x) {
    unsigned int u = __float_as_uint(x);
    // monotone map: orders all floats (incl. negatives) as unsigned
    return (u & 0x80000000u) ? ~u : (u | 0x80000000u);
}

__device__ __forceinline__ unsigned long long pack_key(float v, unsigned int idx) {
    // high word: monotone value bits; low word: ~idx so LOWER index wins ties
    return ((unsigned long long)mono_bits(v) << 32) | (unsigned long long)(~idx);
}

// Single fused kernel:
//   phase 1: per-(sample,chunk) partial argmax over a 64 KB contiguous slice
//            (nontemporal float4 loads: heatmap is single-use stream)
//   phase 2: poison-proof last-block detection per sample -> gather + SSE
//   phase 3: poison-proof global last-sample detection -> exact-order final sum
//
// Flag protocol: publisher release-stores data, then atomicOr(bit) into orf
// and atomicAnd(~bit) into andf, then RE-READS both words. orf/andf carry the
// same unknown poison dword X, so for any bit either the OR side (X=1) or the
// AND side (X=0) can be pre-satisfied — never both. (orf low bits all 1) &&
// (andf low bits all 0) therefore proves every publisher executed its atomics,
// which happen-after its release data store. The block whose atomic lands last
// always observes completion -> guaranteed progress, no spinning, no
// co-residency assumption. Duplicate observers compute identical values.
// SAFETY: even if poison were NOT dword-uniform, the idx clamp below bounds
// every memory access -> no fault is possible for any workspace contents.
__global__ __launch_bounds__(TPB) void fused_kernel(
        const float* __restrict__ heatmap,
        const float* __restrict__ pred,
        const float* __restrict__ gt,
        Ws* ws,
        float* __restrict__ out) {
    const int b     = blockIdx.x / BPS;
    const int chunk = blockIdx.x % BPS;
    const f4* hp = (const f4*)(heatmap + (size_t)b * HW);
    const int vbase = chunk * VEC_PER_CHUNK;

    float m  = -INFINITY;
    f4    sv = {-INFINITY, -INFINITY, -INFINITY, -INFINITY};
    int   si = vbase * 4;

    #pragma unroll 4
    for (int i = threadIdx.x; i < VEC_PER_CHUNK; i += TPB) {
        f4 v = __builtin_nontemporal_load(&hp[vbase + i]);
        float m4 = fmaxf(fmaxf(fmaxf(v.x, v.y), v.z), v.w);   // v_max3 + v_max
        if (m4 > m) {           // strict > keeps earliest occurrence
            m  = m4;
            sv = v;
            si = (vbase + i) * 4;
        }
    }

    unsigned int j = (sv.x == m) ? 0u : (sv.y == m) ? 1u : (sv.z == m) ? 2u : 3u;
    unsigned long long k = pack_key(m, (unsigned int)si + j);

    // wave(64) shuffle reduce on packed keys
    #pragma unroll
    for (int off = 32; off > 0; off >>= 1) {
        unsigned long long o = __shfl_down(k, off, 64);
        if (o > k) k = o;
    }
    __shared__ unsigned long long smax[TPB / 64];
    __shared__ int s_do_final;
    const int lane = threadIdx.x & 63;
    const int wid  = threadIdx.x >> 6;
    if (lane == 0) smax[wid] = k;
    __syncthreads();

    if (threadIdx.x == 0) {
        k = smax[0];
        #pragma unroll
        for (int w = 1; w < TPB / 64; ++w)
            if (smax[w] > k) k = smax[w];

        // publish partial key (release), then flag our chunk bit
        __hip_atomic_store(&ws->part[blockIdx.x], k,
                           __ATOMIC_RELEASE, __HIP_MEMORY_SCOPE_AGENT);
        const unsigned int bit = 1u << chunk;
        __hip_atomic_fetch_or (&ws->orf[b],  bit,
                               __ATOMIC_ACQ_REL, __HIP_MEMORY_SCOPE_AGENT);
        __hip_atomic_fetch_and(&ws->andf[b], ~bit,
                               __ATOMIC_ACQ_REL, __HIP_MEMORY_SCOPE_AGENT);
        unsigned int ov = __hip_atomic_load(&ws->orf[b],
                               __ATOMIC_ACQUIRE, __HIP_MEMORY_SCOPE_AGENT);
        unsigned int av = __hip_atomic_load(&ws->andf[b],
                               __ATOMIC_ACQUIRE, __HIP_MEMORY_SCOPE_AGENT);

        int do_final = 0;
        if (((ov & 0xFFFFu) == 0xFFFFu) && ((av & 0xFFFFu) == 0u)) {
            // sample complete: 16-way key max (order-insensitive, deterministic)
            unsigned long long kk = 0ull;   // valid keys always > 0 (low word ~idx)
            #pragma unroll
            for (int t = 0; t < BPS; ++t) {
                unsigned long long o = __hip_atomic_load(&ws->part[b * BPS + t],
                                           __ATOMIC_RELAXED, __HIP_MEMORY_SCOPE_AGENT);
                if (o > kk) kk = o;
            }
            unsigned int idx = ~(unsigned int)(kk & 0xFFFFFFFFull);
            if (idx >= (unsigned int)HW) idx = HW - 1;   // fault insurance only

            // sequential c-loop: identical FP order to the verified version
            float acc = 0.f;
            for (int c = 0; c < C_DIM; ++c) {
                float d = pred[(size_t)c * HW + idx] - gt[b * C_DIM + c];
                acc += d * d;
            }
            __hip_atomic_store(&ws->sse[b], acc,
                               __ATOMIC_RELEASE, __HIP_MEMORY_SCOPE_AGENT);

            const int word = b >> 5;
            const unsigned int gbit = 1u << (b & 31);
            __hip_atomic_fetch_or (&ws->gor[word],  gbit,
                                   __ATOMIC_ACQ_REL, __HIP_MEMORY_SCOPE_AGENT);
            __hip_atomic_fetch_and(&ws->gand[word], ~gbit,
                                   __ATOMIC_ACQ_REL, __HIP_MEMORY_SCOPE_AGENT);
            int complete = 1;
            #pragma unroll
            for (int w2 = 0; w2 < 4; ++w2) {
                unsigned int go = __hip_atomic_load(&ws->gor[w2],
                                      __ATOMIC_ACQUIRE, __HIP_MEMORY_SCOPE_AGENT);
                unsigned int ga = __hip_atomic_load(&ws->gand[w2],
                                      __ATOMIC_ACQUIRE, __HIP_MEMORY_SCOPE_AGENT);
                if (go != 0xFFFFFFFFu || ga != 0u) complete = 0;
            }
            do_final = complete;
        }
        s_do_final = do_final;
    }
    __syncthreads();

    // Final cross-sample sum: replicate the verified loss_kernel's exact FP
    // order (two 64-lane shuffle trees, then spart[0] + spart[1]).
    if (s_do_final && threadIdx.x < 64) {
        const int l = threadIdx.x;
        float a0 = __hip_atomic_load(&ws->sse[l],
                       __ATOMIC_RELAXED, __HIP_MEMORY_SCOPE_AGENT);
        float a1 = __hip_atomic_load(&ws->sse[64 + l],
                       __ATOMIC_RELAXED, __HIP_MEMORY_SCOPE_AGENT);
        #pragma unroll
        for (int off = 32; off > 0; off >>= 1) {
            a0 += __shfl_down(a0, off, 64);
            a1 += __shfl_down(a1, off, 64);
        }
        if (l == 0) out[0] = a0 + a1;   // idempotent across duplicate finishers
    }
}

extern "C" void kernel_launch(void* const* d_in, const int* in_sizes, int n_in,
                              void* d_out, int out_size, void* d_ws, size_t ws_size,
                              hipStream_t stream) {
    const float* pred    = (const float*)d_in[0];   // [C, H, W]
    const float* gt      = (const float*)d_in[1];   // [B, C]
    const float* heatmap = (const float*)d_in[2];   // [B, H, W]

    fused_kernel<<<B_DIM * BPS, TPB, 0, stream>>>(
        heatmap, pred, gt, (Ws*)d_ws, (float*)d_out);
}

// Round 3
// 205.838 us; speedup vs baseline: 3.8111x; 3.8111x over previous
//
#include <hip/hip_runtime.h>
#include <math.h>

#define C_DIM 16
#define B_DIM 128
#define H_DIM 512
#define W_DIM 512
#define HW (H_DIM * W_DIM)      // 262144
#define BPS 16                  // blocks per sample
#define TPB 256
#define VEC_PER_CHUNK (HW / 4 / BPS)   // 4096 float4 per block

__device__ __forceinline__ unsigned int mono_bits(float x) {
    unsigned int u = __float_as_uint(x);
    // monotone map: orders all floats (incl. negatives) as unsigned
    return (u & 0x80000000u) ? ~u : (u | 0x80000000u);
}

__device__ __forceinline__ unsigned long long pack_key(float v, unsigned int idx) {
    // high word: monotone value bits; low word: ~idx so LOWER index wins ties
    return ((unsigned long long)mono_bits(v) << 32) | (unsigned long long)(~idx);
}

// Stage 1: per-(sample,chunk) partial argmax.
// Inner loop is v_max3-based (~2.5 VALU ops/elem): track the running max value
// plus the float4 + base index where it was found; strictly-greater update
// preserves first-occurrence semantics (thread-local indices are monotone).
// Key packing happens once per thread, after the loop.
// NOTE (R1/R2 post-mortem): do NOT use __builtin_nontemporal_load here and do
// NOT add agent-scope acq/rel atomics at block tails — the fused single-kernel
// variant with those ran 632 us at 108 GB/s (VALUBusy 0.7%): latency/cache-
// maintenance serialization, 30x slower than this verified form (206 us e2e).
__global__ __launch_bounds__(TPB) void argmax_partial_kernel(
        const float* __restrict__ heatmap,
        unsigned long long* __restrict__ part /* [B*BPS], fully overwritten */) {
    const int b     = blockIdx.x / BPS;
    const int chunk = blockIdx.x % BPS;
    const float4* hp = (const float4*)(heatmap + (size_t)b * HW);
    const int vbase = chunk * VEC_PER_CHUNK;

    float  m  = -INFINITY;
    float4 sv = make_float4(-INFINITY, -INFINITY, -INFINITY, -INFINITY);
    int    si = vbase * 4;      // element base index of sv

    #pragma unroll 4
    for (int i = threadIdx.x; i < VEC_PER_CHUNK; i += TPB) {
        float4 v = hp[vbase + i];
        float m4 = fmaxf(fmaxf(fmaxf(v.x, v.y), v.z), v.w);   // v_max3 + v_max
        if (m4 > m) {           // strict > keeps earliest occurrence
            m  = m4;
            sv = v;
            si = (vbase + i) * 4;
        }
    }

    // which element of the saved vector hit the max (first match = lowest idx)
    unsigned int j = (sv.x == m) ? 0u : (sv.y == m) ? 1u : (sv.z == m) ? 2u : 3u;
    unsigned long long k = pack_key(m, (unsigned int)si + j);

    // wave(64) shuffle reduce
    #pragma unroll
    for (int off = 32; off > 0; off >>= 1) {
        unsigned long long o = __shfl_down(k, off, 64);
        if (o > k) k = o;
    }
    __shared__ unsigned long long smax[TPB / 64];
    const int lane = threadIdx.x & 63;
    const int wid  = threadIdx.x >> 6;
    if (lane == 0) smax[wid] = k;
    __syncthreads();
    if (threadIdx.x == 0) {
        k = smax[0];
        #pragma unroll
        for (int w = 1; w < TPB / 64; ++w)
            if (smax[w] > k) k = smax[w];
        part[blockIdx.x] = k;   // plain store — no memset, no atomics
    }
}

// Stage 2: final 16-way key reduce per sample + gather + squared-error sum.
__global__ __launch_bounds__(B_DIM) void loss_kernel(
        const float* __restrict__ pred,
        const float* __restrict__ gt,
        const unsigned long long* __restrict__ part,
        float* __restrict__ out) {
    const int b = threadIdx.x;           // one thread per sample, 2 waves
    unsigned long long k = 0ull;
    #pragma unroll
    for (int j = 0; j < BPS; ++j) {
        unsigned long long o = part[b * BPS + j];
        if (o > k) k = o;
    }
    unsigned int idx = ~(unsigned int)(k & 0xFFFFFFFFull);   // flat H*W index

    float acc = 0.f;
    #pragma unroll
    for (int c = 0; c < C_DIM; ++c) {
        float d = pred[(size_t)c * HW + idx] - gt[b * C_DIM + c];
        acc += d * d;
    }
    // reduce across 128 threads: wave shuffle then LDS
    #pragma unroll
    for (int off = 32; off > 0; off >>= 1)
        acc += __shfl_down(acc, off, 64);
    __shared__ float spart[B_DIM / 64];
    if ((threadIdx.x & 63) == 0) spart[threadIdx.x >> 6] = acc;
    __syncthreads();
    if (threadIdx.x == 0) out[0] = spart[0] + spart[1];
}

extern "C" void kernel_launch(void* const* d_in, const int* in_sizes, int n_in,
                              void* d_out, int out_size, void* d_ws, size_t ws_size,
                              hipStream_t stream) {
    const float* pred    = (const float*)d_in[0];   // [C, H, W]
    const float* gt      = (const float*)d_in[1];   // [B, C]
    const float* heatmap = (const float*)d_in[2];   // [B, H, W]
    float* out = (float*)d_out;
    unsigned long long* part = (unsigned long long*)d_ws;   // [B*BPS] = 16 KB

    argmax_partial_kernel<<<B_DIM * BPS, TPB, 0, stream>>>(heatmap, part);
    loss_kernel<<<1, B_DIM, 0, stream>>>(pred, gt, part, out);
}